// Round 3
// baseline (22.514 us; speedup 1.0000x reference)
//
#include <hip/hip_runtime.h>
#include <math.h>

#define BB 8
#define NN 2048
#define NVARS 64
#define HH 32

// Fully fused: one block per (batch, var) bucket.
//  1. precompute per-var layer-1 base row + folded head (w2g, c)
//  2. scan the batch row for var_id matches -> LDS bucket {t, orig idx}
//  3. MLP (spike_raw) for the bucket's ~N/64 members only
//  4. all-pairs decayed sum within the bucket + tanh epilogue -> out
// Every obs belongs to exactly one bucket, so out is fully written.
__global__ __launch_bounds__(256) void fused_kernel(
    const float* __restrict__ value, const float* __restrict__ time_norm,
    const float* __restrict__ mask,  const int*   __restrict__ var_id,
    const float* __restrict__ var_emb,
    const float* __restrict__ W1, const float* __restrict__ b1,
    const float* __restrict__ W2, const float* __restrict__ b2,
    const float* __restrict__ gate_w, const float* __restrict__ gate_b,
    const float* __restrict__ log_tau_r, const float* __restrict__ log_alpha,
    float* __restrict__ out)
{
    __shared__ float s_t[NN];
    __shared__ float s_sr[NN];
    __shared__ int   s_idx[NN];
    __shared__ float s_base1[HH], s_w1v[HH], s_w1t[HH], s_w1m[HH], s_w2g[HH];
    __shared__ float s_c;
    __shared__ int   s_cnt;

    const int b    = blockIdx.x >> 6;
    const int var  = blockIdx.x & 63;
    const int base = b * NN;
    const int tid  = threadIdx.x;

    if (tid == 0) s_cnt = 0;
    if (tid < HH) {
        // base1[j] = b1[j] + sum_k ve[var,k] * W1[3+k, j]
        float accB = b1[tid];
        #pragma unroll
        for (int k = 0; k < HH; ++k) accB += var_emb[var * HH + k] * W1[(3 + k) * HH + tid];
        s_base1[tid] = accB;
        s_w1v[tid] = W1[0 * HH + tid];
        s_w1t[tid] = W1[1 * HH + tid];
        s_w1m[tid] = W1[2 * HH + tid];
        // w2g = W2 @ gate_w
        float accW = 0.0f;
        #pragma unroll
        for (int i = 0; i < HH; ++i) accW += W2[tid * HH + i] * gate_w[i];
        s_w2g[tid] = accW;
    }
    if (tid == 64) {   // separate wave from the tid<32 work
        float acc = gate_b[0];
        #pragma unroll
        for (int j = 0; j < HH; ++j) acc += b2[j] * gate_w[j];
        s_c = acc;
    }
    __syncthreads();

    // scan the batch row, vectorized x4; append order is irrelevant (strict
    // t_m < t_n makes the pair sum independent of bucket ordering)
    for (int i0 = tid * 4; i0 < NN; i0 += 256 * 4) {
        const int4   v = *reinterpret_cast<const int4*>(var_id + base + i0);
        const float4 t = *reinterpret_cast<const float4*>(time_norm + base + i0);
        if (v.x == var) { int p = atomicAdd(&s_cnt, 1); s_t[p] = t.x; s_idx[p] = i0 + 0; }
        if (v.y == var) { int p = atomicAdd(&s_cnt, 1); s_t[p] = t.y; s_idx[p] = i0 + 1; }
        if (v.z == var) { int p = atomicAdd(&s_cnt, 1); s_t[p] = t.z; s_idx[p] = i0 + 2; }
        if (v.w == var) { int p = atomicAdd(&s_cnt, 1); s_t[p] = t.w; s_idx[p] = i0 + 3; }
    }
    __syncthreads();
    const int S = s_cnt;

    // MLP for bucket members only
    for (int n = tid; n < S; n += 256) {
        const int   gi = base + s_idx[n];
        const float mk = mask[gi];
        const float f0 = value[gi] * mk;
        const float f1 = s_t[n];
        float gate = s_c;
        #pragma unroll
        for (int j = 0; j < HH; ++j) {
            const float pre = s_base1[j] + f0 * s_w1v[j] + f1 * s_w1t[j] + mk * s_w1m[j];
            const float g = 0.5f * pre * (1.0f + erff(pre * 0.70710678118654752f));
            gate = fmaf(g, s_w2g[j], gate);
        }
        s_sr[n] = mk / (1.0f + __expf(-gate));   // sigmoid * mask
    }
    __syncthreads();

    const float inv_tau = 1.0f / fmaxf(__expf(log_tau_r[var]), 1e-6f);
    const float alpha   = __expf(log_alpha[var]);

    // all-pairs decayed sum (LDS broadcast reads) + epilogue
    for (int n = tid; n < S; n += 256) {
        const float t_n = s_t[n];
        float acc = 0.0f;
        for (int m = 0; m < S; ++m) {
            const float td = t_n - s_t[m];
            acc += (td > 0.0f) ? s_sr[m] * __expf(-td * inv_tau) : 0.0f;
        }
        out[base + s_idx[n]] = s_sr[n] * (1.0f - tanhf(alpha * acc));   // FLOOR=0
    }
}

extern "C" void kernel_launch(void* const* d_in, const int* in_sizes, int n_in,
                              void* d_out, int out_size, void* d_ws, size_t ws_size,
                              hipStream_t stream) {
    const float* value     = (const float*)d_in[0];
    const float* time_norm = (const float*)d_in[1];
    const float* mask      = (const float*)d_in[2];
    const int*   var_id    = (const int*)  d_in[3];
    const float* var_emb   = (const float*)d_in[4];
    const float* W1        = (const float*)d_in[5];
    const float* b1        = (const float*)d_in[6];
    const float* W2        = (const float*)d_in[7];
    const float* b2        = (const float*)d_in[8];
    const float* gate_w    = (const float*)d_in[9];
    const float* gate_b    = (const float*)d_in[10];
    const float* log_tau_r = (const float*)d_in[11];
    const float* log_alpha = (const float*)d_in[12];

    float* out = (float*)d_out;

    hipLaunchKernelGGL(fused_kernel, dim3(BB * NVARS), dim3(256), 0, stream,
                       value, time_norm, mask, var_id, var_emb,
                       W1, b1, W2, b2, gate_w, gate_b, log_tau_r, log_alpha, out);
}

// Round 4
// 15.093 us; speedup vs baseline: 1.4917x; 1.4917x over previous
//
#include <hip/hip_runtime.h>
#include <math.h>

#define BB 8
#define NN 2048
#define NVARS 64
#define HH 32

// One block per (batch, var) bucket, single launch.
// Phase A (wave 0):   fold weights -> base1, w1v/t/m, w2g, c
// Phase A' (waves1-3): scan row for var matches -> LDS bucket {t, idx}
// Phase B: lane-parallel MLP  (thread = (obs, hidden j), shfl-reduce)
// Phase C: lane-parallel pairs (thread = (n, m-lane), shfl-reduce) + epilogue
__global__ __launch_bounds__(256) void fused_kernel(
    const float* __restrict__ value, const float* __restrict__ time_norm,
    const float* __restrict__ mask,  const int*   __restrict__ var_id,
    const float* __restrict__ var_emb,
    const float* __restrict__ W1, const float* __restrict__ b1,
    const float* __restrict__ W2, const float* __restrict__ b2,
    const float* __restrict__ gate_w, const float* __restrict__ gate_b,
    const float* __restrict__ log_tau_r, const float* __restrict__ log_alpha,
    float* __restrict__ out)
{
    __shared__ float s_t[NN];
    __shared__ float s_sr[NN];
    __shared__ int   s_idx[NN];
    __shared__ float s_base1[HH], s_w1v[HH], s_w1t[HH], s_w1m[HH], s_w2g[HH];
    __shared__ float s_c;
    __shared__ int   s_cnt;

    const int b    = blockIdx.x >> 6;
    const int var  = blockIdx.x & 63;
    const int base = b * NN;
    const int tid  = threadIdx.x;

    // hoist per-var scalars; overlaps with everything below
    const float inv_tau = 1.0f / fmaxf(__expf(log_tau_r[var]), 1e-6f);
    const float alpha   = __expf(log_alpha[var]);

    if (tid == 0) s_cnt = 0;
    __syncthreads();

    if (tid < 64) {
        if (tid < HH) {
            // base1[j] = b1[j] + sum_k ve[var,k] * W1[3+k, j]
            float accB = b1[tid];
            #pragma unroll
            for (int k = 0; k < HH; ++k) accB += var_emb[var * HH + k] * W1[(3 + k) * HH + tid];
            s_base1[tid] = accB;
            s_w1v[tid] = W1[0 * HH + tid];
            s_w1t[tid] = W1[1 * HH + tid];
            s_w1m[tid] = W1[2 * HH + tid];
            float accW = 0.0f;
            #pragma unroll
            for (int i = 0; i < HH; ++i) accW += W2[tid * HH + i] * gate_w[i];
            s_w2g[tid] = accW;
        } else if (tid == 32) {
            float acc = gate_b[0];
            #pragma unroll
            for (int j = 0; j < HH; ++j) acc += b2[j] * gate_w[j];
            s_c = acc;
        }
    } else {
        // waves 1-3: scan 2048 elems, vec4, 192 threads. Append order is
        // irrelevant (strict t_m < t_n => order-independent pair sum).
        for (int i0 = (tid - 64) * 4; i0 < NN; i0 += 192 * 4) {
            const int4   v = *reinterpret_cast<const int4*>(var_id + base + i0);
            const float4 t = *reinterpret_cast<const float4*>(time_norm + base + i0);
            if (v.x == var) { int p = atomicAdd(&s_cnt, 1); s_t[p] = t.x; s_idx[p] = i0 + 0; }
            if (v.y == var) { int p = atomicAdd(&s_cnt, 1); s_t[p] = t.y; s_idx[p] = i0 + 1; }
            if (v.z == var) { int p = atomicAdd(&s_cnt, 1); s_t[p] = t.z; s_idx[p] = i0 + 2; }
            if (v.w == var) { int p = atomicAdd(&s_cnt, 1); s_t[p] = t.w; s_idx[p] = i0 + 3; }
        }
    }
    __syncthreads();
    const int S = s_cnt;

    const int j   = tid & 31;   // hidden unit / m-lane
    const int sub = tid >> 5;   // 0..7 obs subgroup

    // Phase B: MLP, 8 obs per pass, one GELU term per thread
    for (int n = sub; n < S; n += 8) {
        const int   gi = base + s_idx[n];
        const float mk = mask[gi];
        const float f0 = value[gi] * mk;
        const float f1 = s_t[n];
        const float pre = s_base1[j] + f0 * s_w1v[j] + f1 * s_w1t[j] + mk * s_w1m[j];
        const float g = 0.5f * pre * (1.0f + erff(pre * 0.70710678118654752f));
        float term = g * s_w2g[j];
        #pragma unroll
        for (int off = 16; off > 0; off >>= 1) term += __shfl_xor(term, off, 32);
        if (j == 0) s_sr[n] = mk / (1.0f + __expf(-(term + s_c)));
    }
    __syncthreads();

    // Phase C: pair sums, 8 rows per pass, m strided over 32 lanes
    for (int n = sub; n < S; n += 8) {
        const float t_n = s_t[n];
        float acc = 0.0f;
        for (int m = j; m < S; m += 32) {
            const float td = t_n - s_t[m];
            acc += (td > 0.0f) ? s_sr[m] * __expf(-td * inv_tau) : 0.0f;
        }
        #pragma unroll
        for (int off = 16; off > 0; off >>= 1) acc += __shfl_xor(acc, off, 32);
        if (j == 0) out[base + s_idx[n]] = s_sr[n] * (1.0f - tanhf(alpha * acc));  // FLOOR=0
    }
}

extern "C" void kernel_launch(void* const* d_in, const int* in_sizes, int n_in,
                              void* d_out, int out_size, void* d_ws, size_t ws_size,
                              hipStream_t stream) {
    const float* value     = (const float*)d_in[0];
    const float* time_norm = (const float*)d_in[1];
    const float* mask      = (const float*)d_in[2];
    const int*   var_id    = (const int*)  d_in[3];
    const float* var_emb   = (const float*)d_in[4];
    const float* W1        = (const float*)d_in[5];
    const float* b1        = (const float*)d_in[6];
    const float* W2        = (const float*)d_in[7];
    const float* b2        = (const float*)d_in[8];
    const float* gate_w    = (const float*)d_in[9];
    const float* gate_b    = (const float*)d_in[10];
    const float* log_tau_r = (const float*)d_in[11];
    const float* log_alpha = (const float*)d_in[12];

    float* out = (float*)d_out;

    hipLaunchKernelGGL(fused_kernel, dim3(BB * NVARS), dim3(256), 0, stream,
                       value, time_norm, mask, var_id, var_emb,
                       W1, b1, W2, b2, gate_w, gate_b, log_tau_r, log_alpha, out);
}

// Round 5
// 14.339 us; speedup vs baseline: 1.5701x; 1.0525x over previous
//
#include <hip/hip_runtime.h>
#include <math.h>

#define BB 8
#define NN 2048
#define NVARS 64
#define HH 32

// One block per (batch, var) bucket, single launch.
// Phase A  (wave 0):    fold weights -> base1, w1v/t/m, w2g, c
// Phase A' (waves 1-3): scan row, stash {t, f0=value*mask, mk, idx} in LDS bucket
// Phase B: lane-parallel MLP (thread=(obs,j), shfl-reduce) -> sr, e=sr*exp(t/tau)
// Phase C: pair sum = exp(-t_n/tau) * sum_{t_m<t_n} e_m  -- NO exp in inner loop
__global__ __launch_bounds__(256) void fused_kernel(
    const float* __restrict__ value, const float* __restrict__ time_norm,
    const float* __restrict__ mask,  const int*   __restrict__ var_id,
    const float* __restrict__ var_emb,
    const float* __restrict__ W1, const float* __restrict__ b1,
    const float* __restrict__ W2, const float* __restrict__ b2,
    const float* __restrict__ gate_w, const float* __restrict__ gate_b,
    const float* __restrict__ log_tau_r, const float* __restrict__ log_alpha,
    float* __restrict__ out)
{
    __shared__ float s_t[NN], s_f0[NN], s_mk[NN], s_sr[NN], s_e[NN];
    __shared__ int   s_idx[NN];
    __shared__ float s_base1[HH], s_w1v[HH], s_w1t[HH], s_w1m[HH], s_w2g[HH];
    __shared__ float s_c;
    __shared__ int   s_cnt;

    const int b    = blockIdx.x >> 6;
    const int var  = blockIdx.x & 63;
    const int base = b * NN;
    const int tid  = threadIdx.x;

    const float inv_tau = 1.0f / fmaxf(__expf(log_tau_r[var]), 1e-6f);
    const float alpha   = __expf(log_alpha[var]);

    if (tid == 0) s_cnt = 0;
    __syncthreads();

    if (tid < 64) {
        if (tid < HH) {
            float accB = b1[tid];
            #pragma unroll
            for (int k = 0; k < HH; ++k) accB += var_emb[var * HH + k] * W1[(3 + k) * HH + tid];
            s_base1[tid] = accB;
            s_w1v[tid] = W1[0 * HH + tid];
            s_w1t[tid] = W1[1 * HH + tid];
            s_w1m[tid] = W1[2 * HH + tid];
            float accW = 0.0f;
            #pragma unroll
            for (int i = 0; i < HH; ++i) accW += W2[tid * HH + i] * gate_w[i];
            s_w2g[tid] = accW;
        } else if (tid == 32) {
            float acc = gate_b[0];
            #pragma unroll
            for (int j = 0; j < HH; ++j) acc += b2[j] * gate_w[j];
            s_c = acc;
        }
    } else {
        // waves 1-3: coalesced vec4 scan; stash everything Phase B needs.
        // Append order irrelevant (strict t_m < t_n => order-independent sum).
        for (int i0 = (tid - 64) * 4; i0 < NN; i0 += 192 * 4) {
            const int4   v  = *reinterpret_cast<const int4*>(var_id + base + i0);
            const float4 t  = *reinterpret_cast<const float4*>(time_norm + base + i0);
            const float4 vl = *reinterpret_cast<const float4*>(value + base + i0);
            const float4 mk = *reinterpret_cast<const float4*>(mask + base + i0);
            if (v.x == var) { int p = atomicAdd(&s_cnt, 1); s_t[p] = t.x; s_f0[p] = vl.x * mk.x; s_mk[p] = mk.x; s_idx[p] = i0 + 0; }
            if (v.y == var) { int p = atomicAdd(&s_cnt, 1); s_t[p] = t.y; s_f0[p] = vl.y * mk.y; s_mk[p] = mk.y; s_idx[p] = i0 + 1; }
            if (v.z == var) { int p = atomicAdd(&s_cnt, 1); s_t[p] = t.z; s_f0[p] = vl.z * mk.z; s_mk[p] = mk.z; s_idx[p] = i0 + 2; }
            if (v.w == var) { int p = atomicAdd(&s_cnt, 1); s_t[p] = t.w; s_f0[p] = vl.w * mk.w; s_mk[p] = mk.w; s_idx[p] = i0 + 3; }
        }
    }
    __syncthreads();
    const int S = s_cnt;

    const int j   = tid & 31;   // hidden unit / m-lane
    const int sub = tid >> 5;   // 0..7 obs subgroup

    // Phase B: MLP, 8 obs per pass, one GELU term per thread; LDS-only inputs
    for (int n = sub; n < S; n += 8) {
        const float mk = s_mk[n];
        const float f0 = s_f0[n];
        const float f1 = s_t[n];
        const float pre = s_base1[j] + f0 * s_w1v[j] + f1 * s_w1t[j] + mk * s_w1m[j];
        const float g = 0.5f * pre * (1.0f + erff(pre * 0.70710678118654752f));
        float term = g * s_w2g[j];
        #pragma unroll
        for (int off = 16; off > 0; off >>= 1) term += __shfl_xor(term, off, 32);
        if (j == 0) {
            const float sr = mk / (1.0f + __expf(-(term + s_c)));
            s_sr[n] = sr;
            s_e[n]  = sr * __expf(f1 * inv_tau);   // factored decay term
        }
    }
    __syncthreads();

    // Phase C: pure FMA inner loop (decay factored out of the pair)
    for (int n = sub; n < S; n += 8) {
        const float t_n = s_t[n];
        float acc = 0.0f;
        for (int m = j; m < S; m += 32)
            acc += (s_t[m] < t_n) ? s_e[m] : 0.0f;
        #pragma unroll
        for (int off = 16; off > 0; off >>= 1) acc += __shfl_xor(acc, off, 32);
        if (j == 0) {
            const float refr = acc * __expf(-t_n * inv_tau);
            out[base + s_idx[n]] = s_sr[n] * (1.0f - tanhf(alpha * refr));  // FLOOR=0
        }
    }
}

extern "C" void kernel_launch(void* const* d_in, const int* in_sizes, int n_in,
                              void* d_out, int out_size, void* d_ws, size_t ws_size,
                              hipStream_t stream) {
    const float* value     = (const float*)d_in[0];
    const float* time_norm = (const float*)d_in[1];
    const float* mask      = (const float*)d_in[2];
    const int*   var_id    = (const int*)  d_in[3];
    const float* var_emb   = (const float*)d_in[4];
    const float* W1        = (const float*)d_in[5];
    const float* b1        = (const float*)d_in[6];
    const float* W2        = (const float*)d_in[7];
    const float* b2        = (const float*)d_in[8];
    const float* gate_w    = (const float*)d_in[9];
    const float* gate_b    = (const float*)d_in[10];
    const float* log_tau_r = (const float*)d_in[11];
    const float* log_alpha = (const float*)d_in[12];

    float* out = (float*)d_out;

    hipLaunchKernelGGL(fused_kernel, dim3(BB * NVARS), dim3(256), 0, stream,
                       value, time_norm, mask, var_id, var_emb,
                       W1, b1, W2, b2, gate_w, gate_b, log_tau_r, log_alpha, out);
}